// Round 3
// baseline (802.678 us; speedup 1.0000x reference)
//
#include <hip/hip_runtime.h>

typedef unsigned short u16;
using bf16x8 = __attribute__((ext_vector_type(8))) __bf16;
using f32x4  = __attribute__((ext_vector_type(4))) float;

__device__ __forceinline__ u16 f2bf(float f) {
    unsigned u = __builtin_bit_cast(unsigned, f);
    u += 0x7fffu + ((u >> 16) & 1u);
    return (u16)(u >> 16);
}
__device__ __forceinline__ float bf2f(u16 h) {
    unsigned u = ((unsigned)h) << 16;
    return __builtin_bit_cast(float, u);
}

__device__ __forceinline__ float wred_max(float v) {
    #pragma unroll
    for (int o = 32; o; o >>= 1) v = fmaxf(v, __shfl_xor(v, o, 64));
    return v;
}
__device__ __forceinline__ float wred_sum(float v) {
    #pragma unroll
    for (int o = 32; o; o >>= 1) v += __shfl_xor(v, o, 64);
    return v;
}

// async global->LDS, 16B per lane. LDS dest must be wave-uniform base + lane*16.
__device__ __forceinline__ void gl2lds16(const u16* g, void* l) {
    __builtin_amdgcn_global_load_lds(
        (__attribute__((address_space(1))) void*)(g),
        (__attribute__((address_space(3))) void*)(l), 16, 0, 0);
}

// ---------------------------------------------------------------- cast fp32->bf16
__global__ __launch_bounds__(256)
void cast_bf16(const float* __restrict__ src, u16* __restrict__ dst, int n4) {
    int i = blockIdx.x * 256 + threadIdx.x;
    if (i < n4) {
        float4 f = ((const float4*)src)[i];
        ushort4 u;
        u.x = f2bf(f.x); u.y = f2bf(f.y); u.z = f2bf(f.z); u.w = f2bf(f.w);
        ((ushort4*)dst)[i] = u;
    }
}

// ---------------------------------------------------------------- GEMM C = A * Bt^T
// A: [M,K] bf16 row-major.  Bt: [N,K] bf16 row-major (K contiguous).
// Tile TM x 128, 256 threads (4 waves, 2x2), BK=32, mfma 16x16x32, direct-to-LDS staging.
// MODE 0: QKV projection epilogue (bias; Q,K row-major; V transposed via LDS to Vt[b][e][n]).
// MODE 1: scale + bf16 store to oS.
// MODE 2: fp32 atomicAdd into oF (split-K via blockIdx.z, KS = K-slice length).
template<int MODE, int TM>
__global__ __launch_bounds__(256, 4)
void gemm_bt(const u16* __restrict__ A, const u16* __restrict__ Bt,
             const int M, const int N, const int K, const int KS,
             u16* __restrict__ oQ, u16* __restrict__ oK, u16* __restrict__ oVt,
             const float* __restrict__ bQ, const float* __restrict__ bK,
             const float* __restrict__ bV,
             u16* __restrict__ oS, float* __restrict__ oF, const float scale)
{
    __shared__ u16 smem[TM * 32 + 128 * 32];
    u16* As = smem;
    u16* Bs = smem + TM * 32;

    constexpr int IM = TM / 32;         // per-wave m-tiles of 16
    const int tid  = threadIdx.x;
    const int wv   = tid >> 6;
    const int lane = tid & 63;
    const int wr   = (wv >> 1) * (TM / 2);
    const int wc   = (wv & 1) << 6;

    const int row0 = blockIdx.y * TM;
    const int col0 = blockIdx.x * 128;

    // staging: thread tid covers 16B chunk tid of each 64-row half-tile
    const int srow = tid >> 2;          // 0..63
    const int scol = (tid & 3) << 3;    // 0,8,16,24 (bf16 units)

    const u16* pA0 = A  + (size_t)(row0 + srow) * K + scol;
    const u16* pB0 = Bt + (size_t)(col0 + srow) * K + scol;

    // wave-uniform LDS bases (lane*16 appended by HW)
    char* aB0 = (char*)As + wv * 1024;
    char* aB1 = (char*)As + 4096 + wv * 1024;
    char* bB0 = (char*)Bs + wv * 1024;
    char* bB1 = (char*)Bs + 4096 + wv * 1024;

    const int fr = lane & 15;
    const int kc = (lane >> 4) << 3;

    f32x4 acc[IM][4];
    #pragma unroll
    for (int i = 0; i < IM; i++)
        #pragma unroll
        for (int j = 0; j < 4; j++) acc[i][j] = (f32x4){0.f, 0.f, 0.f, 0.f};

    const int kBeg = KS ? (int)blockIdx.z * KS : 0;
    const int kEnd = KS ? kBeg + KS : K;

    for (int k0 = kBeg; k0 < kEnd; k0 += 32) {
        __syncthreads();
        gl2lds16(pA0 + k0, aB0);
        if (TM == 128) gl2lds16(pA0 + (size_t)64 * K + k0, aB1);
        gl2lds16(pB0 + k0, bB0);
        gl2lds16(pB0 + (size_t)64 * K + k0, bB1);
        __syncthreads();

        bf16x8 af[IM], bfr[4];
        #pragma unroll
        for (int i = 0; i < IM; i++) af[i]  = *(const bf16x8*)&As[(wr + 16 * i + fr) * 32 + kc];
        #pragma unroll
        for (int j = 0; j < 4; j++)  bfr[j] = *(const bf16x8*)&Bs[(wc + 16 * j + fr) * 32 + kc];
        #pragma unroll
        for (int i = 0; i < IM; i++)
            #pragma unroll
            for (int j = 0; j < 4; j++)
                acc[i][j] = __builtin_amdgcn_mfma_f32_16x16x32_bf16(af[i], bfr[j], acc[i][j], 0, 0, 0);
    }

    // epilogue: C/D layout col = lane&15, row = (lane>>4)*4 + reg
    const int rB = (lane >> 4) << 2;
    const int cB = lane & 15;

    if (MODE == 0) {
        const int sel = col0 >> 10;     // 0=Q 1=K 2=V (blocks never straddle)
        if (sel < 2) {
            const float* bias = (sel == 0) ? bQ : bK;
            u16* dst = (sel == 0) ? oQ : oK;
            #pragma unroll
            for (int i = 0; i < IM; i++) {
                #pragma unroll
                for (int j = 0; j < 4; j++) {
                    const int m0 = row0 + wr + 16 * i + rB;
                    const int e  = (col0 & 1023) + wc + 16 * j + cB;
                    const float bb = bias[e];
                    #pragma unroll
                    for (int t = 0; t < 4; t++)
                        dst[(size_t)(m0 + t) * 1024 + e] = f2bf(acc[i][j][t] + bb);
                }
            }
        } else {
            // V: transpose 128x128 tile through LDS (XOR-swizzled), write Vt[b][e][n]
            // coalesced 16B/lane. Two passes of 64 e-rows (8192 u16 buffer = smem).
            const int b      = row0 >> 12;
            const int n_base = row0 & 4095;
            const int e0     = col0 & 1023;
            __syncthreads();            // K-loop LDS reads done; smem reused
            #pragma unroll
            for (int P = 0; P < 2; ++P) {
                if ((wc >> 6) == P) {   // waves holding e_l in [64P, 64P+64)
                    #pragma unroll
                    for (int i = 0; i < IM; i++) {
                        const int n_l0 = wr + 16 * i + rB;
                        const int hq   = n_l0 >> 3;
                        const int off  = n_l0 & 7;
                        #pragma unroll
                        for (int j = 0; j < 4; j++) {
                            const int e_p = 16 * j + cB;          // 0..63
                            const int hp  = hq ^ (e_p & 7);
                            const float bb = bV[e0 + P * 64 + e_p];
                            ushort4 pk;
                            pk.x = f2bf(acc[i][j][0] + bb);
                            pk.y = f2bf(acc[i][j][1] + bb);
                            pk.z = f2bf(acc[i][j][2] + bb);
                            pk.w = f2bf(acc[i][j][3] + bb);
                            *(ushort4*)&smem[e_p * 128 + hp * 8 + off] = pk;
                        }
                    }
                }
                __syncthreads();
                #pragma unroll
                for (int p4 = 0; p4 < 4; ++p4) {
                    const int idx = p4 * 256 + tid;               // 0..1023
                    const int er  = idx >> 4;                     // 0..63
                    const int c   = idx & 15;
                    const int cc  = c ^ (er & 7);
                    int4 v = *(const int4*)&smem[er * 128 + cc * 8];
                    *(int4*)&oVt[(size_t)b * 4194304 +
                                 (size_t)(e0 + P * 64 + er) * 4096 + n_base + c * 8] = v;
                }
                if (P == 0) __syncthreads();
            }
        }
    } else if (MODE == 1) {
        #pragma unroll
        for (int i = 0; i < IM; i++)
            #pragma unroll
            for (int j = 0; j < 4; j++) {
                const int m0 = row0 + wr + 16 * i + rB;
                const int c  = col0 + wc + 16 * j + cB;
                #pragma unroll
                for (int t = 0; t < 4; t++)
                    oS[(size_t)(m0 + t) * N + c] = f2bf(acc[i][j][t] * scale);
            }
    } else {
        #pragma unroll
        for (int i = 0; i < IM; i++)
            #pragma unroll
            for (int j = 0; j < 4; j++) {
                const int m0 = row0 + wr + 16 * i + rB;
                const int c  = col0 + wc + 16 * j + cB;
                #pragma unroll
                for (int t = 0; t < 4; t++)
                    atomicAdd(&oF[(size_t)(m0 + t) * N + c], acc[i][j][t]);
            }
    }
}

// ---------------------------------------------------------------- row softmax (in place), row len 4096 bf16
__global__ __launch_bounds__(256)
void softmax_rows(u16* __restrict__ P) {
    const size_t row = blockIdx.x;
    u16* p = P + (row << 12);
    const int t = threadIdx.x;
    const int wv = t >> 6, lane = t & 63;

    u16 u[16];
    *(int4*)&u[0] = *(const int4*)(p + t * 16);
    *(int4*)&u[8] = *(const int4*)(p + t * 16 + 8);
    float v[16];
    #pragma unroll
    for (int i = 0; i < 16; i++) v[i] = bf2f(u[i]);

    float m = v[0];
    #pragma unroll
    for (int i = 1; i < 16; i++) m = fmaxf(m, v[i]);
    m = wred_max(m);
    __shared__ float sm[4];
    __shared__ float ss[4];
    if (lane == 0) sm[wv] = m;
    __syncthreads();
    m = fmaxf(fmaxf(sm[0], sm[1]), fmaxf(sm[2], sm[3]));

    float s = 0.f;
    #pragma unroll
    for (int i = 0; i < 16; i++) { v[i] = __expf(v[i] - m); s += v[i]; }
    s = wred_sum(s);
    if (lane == 0) ss[wv] = s;
    __syncthreads();
    s = ss[0] + ss[1] + ss[2] + ss[3];
    const float inv = 1.0f / s;

    #pragma unroll
    for (int i = 0; i < 16; i++) u[i] = f2bf(v[i] * inv);
    *(int4*)(p + t * 16)     = *(const int4*)&u[0];
    *(int4*)(p + t * 16 + 8) = *(const int4*)&u[8];
}

// ---------------------------------------------------------------- residual + LayerNorm (in place on out)
__global__ __launch_bounds__(256)
void residual_ln(const float* __restrict__ emb, float* __restrict__ out,
                 const float* __restrict__ gamma, const float* __restrict__ beta) {
    const size_t row = blockIdx.x;
    const int t = threadIdx.x;
    const int wv = t >> 6, lane = t & 63;
    const size_t base = row * 1024 + t * 4;

    float4 ev = *(const float4*)(emb + base);
    float4 ov = *(const float4*)(out + base);
    float x0 = ev.x + ov.x, x1 = ev.y + ov.y, x2 = ev.z + ov.z, x3 = ev.w + ov.w;

    float s = x0 + x1 + x2 + x3;
    float q = x0 * x0 + x1 * x1 + x2 * x2 + x3 * x3;
    s = wred_sum(s);
    q = wred_sum(q);
    __shared__ float s1[4], s2[4];
    if (lane == 0) { s1[wv] = s; s2[wv] = q; }
    __syncthreads();
    s = s1[0] + s1[1] + s1[2] + s1[3];
    q = s2[0] + s2[1] + s2[2] + s2[3];

    const float mu  = s * (1.0f / 1024.0f);
    const float var = q * (1.0f / 1024.0f) - mu * mu;
    const float r   = rsqrtf(var + 1e-5f);

    float4 g  = *(const float4*)(gamma + t * 4);
    float4 be = *(const float4*)(beta + t * 4);
    float4 res;
    res.x = (x0 - mu) * r * g.x + be.x;
    res.y = (x1 - mu) * r * g.y + be.y;
    res.z = (x2 - mu) * r * g.z + be.z;
    res.w = (x3 - mu) * r * g.w + be.w;
    *(float4*)(out + base) = res;
}

// ---------------------------------------------------------------- launch
extern "C" void kernel_launch(void* const* d_in, const int* in_sizes, int n_in,
                              void* d_out, int out_size, void* d_ws, size_t ws_size,
                              hipStream_t stream) {
    const float* emb   = (const float*)d_in[0];
    const float* Wq    = (const float*)d_in[4];
    const float* bq    = (const float*)d_in[5];
    const float* Wk    = (const float*)d_in[6];
    const float* bk    = (const float*)d_in[7];
    const float* Wv    = (const float*)d_in[8];
    const float* bv    = (const float*)d_in[9];
    const float* gamma = (const float*)d_in[10];
    const float* beta  = (const float*)d_in[11];
    float* out = (float*)d_out;

    char* ws = (char*)d_ws;
    // layout (bytes):
    //   [0,          33554432)  Xbf bf16 [16384,1024]  -- later reused as P [4096,4096] bf16
    //   [33554432,   39845888)  Wbf bf16 [3072,1024]   (Wq|Wk|Wv rows)
    //   [39845888,   73400320)  Qbf bf16 [16384,1024]
    //   [73400320,  106954752)  Kbf bf16 [16384,1024]
    //   [106954752, 140509184)  Vt  bf16 [4][1024][4096]
    if (ws_size < 140509184u) return;
    u16* Xbf = (u16*)(ws);
    u16* Wbf = (u16*)(ws + 33554432);
    u16* Qbf = (u16*)(ws + 39845888);
    u16* Kbf = (u16*)(ws + 73400320);
    u16* Vt  = (u16*)(ws + 106954752);

    cast_bf16<<<16384, 256, 0, stream>>>(emb, Xbf, 4194304);
    cast_bf16<<<1024, 256, 0, stream>>>(Wq, Wbf,           262144);
    cast_bf16<<<1024, 256, 0, stream>>>(Wk, Wbf + 1048576, 262144);
    cast_bf16<<<1024, 256, 0, stream>>>(Wv, Wbf + 2097152, 262144);

    // out accumulates PV via atomics -> zero it (harness poisons it to 0xAA)
    hipMemsetAsync(out, 0, (size_t)out_size * 4, stream);

    // fused QKV projection: [16384,3072] = Xbf @ Wbf^T + bias
    gemm_bt<0, 128><<<dim3(24, 128), 256, 0, stream>>>(Xbf, Wbf, 16384, 3072, 1024, 0,
        Qbf, Kbf, Vt, bq, bk, bv, nullptr, nullptr, 1.0f);

    u16* P = Xbf;  // reuse
    for (int b = 0; b < 4; ++b) {
        const size_t o = (size_t)b * 4194304;  // 4096*1024
        // S = (Q K^T) / 32  -> bf16 [4096,4096]
        gemm_bt<1, 128><<<dim3(32, 32), 256, 0, stream>>>(Qbf + o, Kbf + o, 4096, 4096, 1024, 0,
            nullptr, nullptr, nullptr, nullptr, nullptr, nullptr, P, nullptr, 0.03125f);
        softmax_rows<<<4096, 256, 0, stream>>>(P);
        // O = P @ V: TM=128, split-K=2 (grid z), fp32 atomicAdd into out
        gemm_bt<2, 128><<<dim3(8, 32, 2), 256, 0, stream>>>(P, Vt + o, 4096, 1024, 4096, 2048,
            nullptr, nullptr, nullptr, nullptr, nullptr, nullptr, nullptr, out + o, 1.0f);
    }

    residual_ln<<<16384, 256, 0, stream>>>(emb, out, gamma, beta);
}

// Round 4
// 742.960 us; speedup vs baseline: 1.0804x; 1.0804x over previous
//
#include <hip/hip_runtime.h>
#include <hip/hip_fp8.h>

typedef unsigned short u16;
typedef unsigned char  u8;
typedef long long      i64;
using bf16x8 = __attribute__((ext_vector_type(8))) __bf16;
using f32x4  = __attribute__((ext_vector_type(4))) float;

__device__ __forceinline__ u16 f2bf(float f) {
    unsigned u = __builtin_bit_cast(unsigned, f);
    u += 0x7fffu + ((u >> 16) & 1u);
    return (u16)(u >> 16);
}
__device__ __forceinline__ float bf2f(u16 h) {
    unsigned u = ((unsigned)h) << 16;
    return __builtin_bit_cast(float, u);
}
__device__ __forceinline__ u8 f2fp8(float f) {
    __hip_fp8_e4m3 t(f);
    return t.__x;
}
__device__ __forceinline__ float wred_sum(float v) {
    #pragma unroll
    for (int o = 32; o; o >>= 1) v += __shfl_xor(v, o, 64);
    return v;
}

// async global->LDS, 16B per lane. LDS dest must be wave-uniform base + lane*16.
__device__ __forceinline__ void gl2lds16(const void* g, void* l) {
    __builtin_amdgcn_global_load_lds(
        (__attribute__((address_space(1))) void*)(g),
        (__attribute__((address_space(3))) void*)(l), 16, 0, 0);
}

// ---------------------------------------------------------------- cast fp32->bf16
__global__ __launch_bounds__(256)
void cast_bf16(const float* __restrict__ src, u16* __restrict__ dst, int n4) {
    int i = blockIdx.x * 256 + threadIdx.x;
    if (i < n4) {
        float4 f = ((const float4*)src)[i];
        ushort4 u;
        u.x = f2bf(f.x); u.y = f2bf(f.y); u.z = f2bf(f.z); u.w = f2bf(f.w);
        ((ushort4*)dst)[i] = u;
    }
}

// ---------------------------------------------------------------- cast bf16 -> fp8 e4m3 (8 elems/thread)
__global__ __launch_bounds__(256)
void cast_v_fp8(const u16* __restrict__ src, u8* __restrict__ dst, int n8) {
    int i = blockIdx.x * 256 + threadIdx.x;
    if (i < n8) {
        ushort4 a = ((const ushort4*)src)[2 * i];
        ushort4 b = ((const ushort4*)src)[2 * i + 1];
        union { u8 c[8]; unsigned long long q; } r;
        r.c[0] = f2fp8(bf2f(a.x)); r.c[1] = f2fp8(bf2f(a.y));
        r.c[2] = f2fp8(bf2f(a.z)); r.c[3] = f2fp8(bf2f(a.w));
        r.c[4] = f2fp8(bf2f(b.x)); r.c[5] = f2fp8(bf2f(b.y));
        r.c[6] = f2fp8(bf2f(b.z)); r.c[7] = f2fp8(bf2f(b.w));
        ((unsigned long long*)dst)[i] = r.q;
    }
}

// ---------------------------------------------------------------- GEMM C = A * Bt^T (bf16 inputs)
// A: [M,K] bf16 row-major.  Bt: [N,K] bf16 row-major (K contiguous). K=1024 here.
// Tile TM x 128, 256 threads (4 waves, 2x2), BK=32, mfma 16x16x32, direct-to-LDS staging.
// MODE 0: QKV projection epilogue (bias; Q,K bf16 row-major; V transposed via LDS to Vt bf16).
// MODE 1: P = exp(acc*scale) -> fp8 e4m3 [.,4096], plus atomic row-sum accumulation into sums[].
template<int MODE, int TM>
__global__ __launch_bounds__(256, 4)
void gemm_bt(const u16* __restrict__ A, const u16* __restrict__ Bt, const int K,
             u16* __restrict__ oQ, u16* __restrict__ oK, u16* __restrict__ oVt,
             const float* __restrict__ bQ, const float* __restrict__ bK,
             const float* __restrict__ bV,
             u8* __restrict__ oP, float* __restrict__ sums, const float scale)
{
    __shared__ u16 smem[TM * 32 + 128 * 32];
    u16* As = smem;
    u16* Bs = smem + TM * 32;

    constexpr int IM = TM / 32;
    const int tid  = threadIdx.x;
    const int wv   = tid >> 6;
    const int lane = tid & 63;
    const int wr   = (wv >> 1) * (TM / 2);
    const int wc   = (wv & 1) << 6;

    const int row0 = blockIdx.y * TM;
    const int col0 = blockIdx.x * 128;

    const int srow = tid >> 2;
    const int scol = (tid & 3) << 3;

    const u16* pA0 = A  + (size_t)(row0 + srow) * K + scol;
    const u16* pB0 = Bt + (size_t)(col0 + srow) * K + scol;

    char* aB0 = (char*)As + wv * 1024;
    char* aB1 = (char*)As + 4096 + wv * 1024;
    char* bB0 = (char*)Bs + wv * 1024;
    char* bB1 = (char*)Bs + 4096 + wv * 1024;

    const int fr = lane & 15;
    const int kc = (lane >> 4) << 3;

    f32x4 acc[IM][4];
    #pragma unroll
    for (int i = 0; i < IM; i++)
        #pragma unroll
        for (int j = 0; j < 4; j++) acc[i][j] = (f32x4){0.f, 0.f, 0.f, 0.f};

    for (int k0 = 0; k0 < K; k0 += 32) {
        __syncthreads();
        gl2lds16(pA0 + k0, aB0);
        if (TM == 128) gl2lds16(pA0 + (size_t)64 * K + k0, aB1);
        gl2lds16(pB0 + k0, bB0);
        gl2lds16(pB0 + (size_t)64 * K + k0, bB1);
        __syncthreads();

        bf16x8 af[IM], bfr[4];
        #pragma unroll
        for (int i = 0; i < IM; i++) af[i]  = *(const bf16x8*)&As[(wr + 16 * i + fr) * 32 + kc];
        #pragma unroll
        for (int j = 0; j < 4; j++)  bfr[j] = *(const bf16x8*)&Bs[(wc + 16 * j + fr) * 32 + kc];
        #pragma unroll
        for (int i = 0; i < IM; i++)
            #pragma unroll
            for (int j = 0; j < 4; j++)
                acc[i][j] = __builtin_amdgcn_mfma_f32_16x16x32_bf16(af[i], bfr[j], acc[i][j], 0, 0, 0);
    }

    // epilogue: C/D layout col = lane&15, row = (lane>>4)*4 + reg
    const int rB = (lane >> 4) << 2;
    const int cB = lane & 15;

    if (MODE == 0) {
        const int sel = col0 >> 10;     // 0=Q 1=K 2=V
        if (sel < 2) {
            const float* bias = (sel == 0) ? bQ : bK;
            u16* dst = (sel == 0) ? oQ : oK;
            #pragma unroll
            for (int i = 0; i < IM; i++) {
                #pragma unroll
                for (int j = 0; j < 4; j++) {
                    const int m0 = row0 + wr + 16 * i + rB;
                    const int e  = (col0 & 1023) + wc + 16 * j + cB;
                    const float bb = bias[e];
                    #pragma unroll
                    for (int t = 0; t < 4; t++)
                        dst[(size_t)(m0 + t) * 1024 + e] = f2bf(acc[i][j][t] + bb);
                }
            }
        } else {
            // V: transpose 128x128 tile through LDS (XOR-swizzled), write Vt[b][e][n] bf16
            const int b      = row0 >> 12;
            const int n_base = row0 & 4095;
            const int e0     = col0 & 1023;
            __syncthreads();
            #pragma unroll
            for (int P = 0; P < 2; ++P) {
                if ((wc >> 6) == P) {
                    #pragma unroll
                    for (int i = 0; i < IM; i++) {
                        const int n_l0 = wr + 16 * i + rB;
                        const int hq   = n_l0 >> 3;
                        const int off  = n_l0 & 7;
                        #pragma unroll
                        for (int j = 0; j < 4; j++) {
                            const int e_p = 16 * j + cB;
                            const int hp  = hq ^ (e_p & 7);
                            const float bb = bV[e0 + P * 64 + e_p];
                            ushort4 pk;
                            pk.x = f2bf(acc[i][j][0] + bb);
                            pk.y = f2bf(acc[i][j][1] + bb);
                            pk.z = f2bf(acc[i][j][2] + bb);
                            pk.w = f2bf(acc[i][j][3] + bb);
                            *(ushort4*)&smem[e_p * 128 + hp * 8 + off] = pk;
                        }
                    }
                }
                __syncthreads();
                #pragma unroll
                for (int p4 = 0; p4 < 4; ++p4) {
                    const int idx = p4 * 256 + tid;
                    const int er  = idx >> 4;
                    const int c   = idx & 15;
                    const int cc  = c ^ (er & 7);
                    int4 v = *(const int4*)&smem[er * 128 + cc * 8];
                    *(int4*)&oVt[(size_t)b * 4194304 +
                                 (size_t)(e0 + P * 64 + er) * 4096 + n_base + c * 8] = v;
                }
                if (P == 0) __syncthreads();
            }
        }
    } else {
        // MODE 1: exp -> fp8 P + row-sum atomics
        float psum[IM][4];
        #pragma unroll
        for (int i = 0; i < IM; i++)
            #pragma unroll
            for (int t = 0; t < 4; t++) psum[i][t] = 0.f;

        #pragma unroll
        for (int i = 0; i < IM; i++) {
            #pragma unroll
            for (int j = 0; j < 4; j++) {
                const int m0 = row0 + wr + 16 * i + rB;
                const int c  = col0 + wc + 16 * j + cB;
                #pragma unroll
                for (int t = 0; t < 4; t++) {
                    const float e = __expf(acc[i][j][t] * scale);
                    psum[i][t] += e;
                    oP[(size_t)(m0 + t) * 4096 + c] = f2fp8(e);
                }
            }
        }
        #pragma unroll
        for (int i = 0; i < IM; i++) {
            #pragma unroll
            for (int t = 0; t < 4; t++) {
                float v = psum[i][t];
                v += __shfl_xor(v, 1, 64);
                v += __shfl_xor(v, 2, 64);
                v += __shfl_xor(v, 4, 64);
                v += __shfl_xor(v, 8, 64);
                if (cB == 0)
                    atomicAdd(&sums[row0 + wr + 16 * i + rB + t], v);
            }
        }
    }
}

// ---------------------------------------------------------------- batched PV, fp8: O[b][m][e] = sum_n P[m][n] Vt[e][n] / rowsum
__global__ __launch_bounds__(256, 4)
void pv_fp8(const u8* __restrict__ p0, const u8* __restrict__ p1,
            const u8* __restrict__ p2, const u8* __restrict__ p3,
            const u8* __restrict__ vt8, const float* __restrict__ sums,
            float* __restrict__ out)
{
    __shared__ u8 As[128 * 64];   // P tile: 128 m x 64 n
    __shared__ u8 Bs[128 * 64];   // Vt tile: 128 e x 64 n

    const int b = blockIdx.z;
    const u8* Pb = (b == 0) ? p0 : (b == 1) ? p1 : (b == 2) ? p2 : p3;
    const u8* Vb = vt8 + (size_t)b * 4194304;
    const float* sm = sums + (b << 12);
    float* Ob = out + (size_t)b * 4194304;

    const int tid = threadIdx.x, wv = tid >> 6, lane = tid & 63;
    const int wr = (wv >> 1) << 6, wc = (wv & 1) << 6;
    const int row0 = blockIdx.y << 7, col0 = blockIdx.x << 7;

    // staging: chunk c = tid (rows 0..63) and tid+256 (rows 64..127); 64 B/row
    const u8* gA0 = Pb + (size_t)(row0 + (tid >> 2)) * 4096 + ((tid & 3) << 4);
    const u8* gA1 = gA0 + (size_t)64 * 4096;
    const u8* gB0 = Vb + (size_t)(col0 + (tid >> 2)) * 4096 + ((tid & 3) << 4);
    const u8* gB1 = gB0 + (size_t)64 * 4096;
    char* aL0 = (char*)As + wv * 1024;
    char* aL1 = (char*)As + 4096 + wv * 1024;
    char* bL0 = (char*)Bs + wv * 1024;
    char* bL1 = (char*)Bs + 4096 + wv * 1024;

    const int fr = lane & 15;
    const int kb = (lane >> 4) << 3;   // byte offset of 8-byte k-group within 32

    f32x4 acc[4][4];
    #pragma unroll
    for (int i = 0; i < 4; i++)
        #pragma unroll
        for (int j = 0; j < 4; j++) acc[i][j] = (f32x4){0.f, 0.f, 0.f, 0.f};

    for (int n0 = 0; n0 < 4096; n0 += 64) {
        __syncthreads();
        gl2lds16(gA0 + n0, aL0);
        gl2lds16(gA1 + n0, aL1);
        gl2lds16(gB0 + n0, bL0);
        gl2lds16(gB1 + n0, bL1);
        __syncthreads();
        #pragma unroll
        for (int kk = 0; kk < 64; kk += 32) {
            i64 af[4], bf[4];
            #pragma unroll
            for (int i = 0; i < 4; i++) af[i] = *(const i64*)&As[(wr + 16 * i + fr) * 64 + kk + kb];
            #pragma unroll
            for (int j = 0; j < 4; j++) bf[j] = *(const i64*)&Bs[(wc + 16 * j + fr) * 64 + kk + kb];
            #pragma unroll
            for (int i = 0; i < 4; i++)
                #pragma unroll
                for (int j = 0; j < 4; j++)
                    acc[i][j] = __builtin_amdgcn_mfma_f32_16x16x32_fp8_fp8(af[i], bf[j], acc[i][j], 0, 0, 0);
        }
    }

    const int rB = (lane >> 4) << 2, cB = lane & 15;
    #pragma unroll
    for (int i = 0; i < 4; i++) {
        const int m0 = row0 + wr + 16 * i + rB;
        const float i0 = 1.0f / sm[m0];
        const float i1 = 1.0f / sm[m0 + 1];
        const float i2 = 1.0f / sm[m0 + 2];
        const float i3 = 1.0f / sm[m0 + 3];
        #pragma unroll
        for (int j = 0; j < 4; j++) {
            const int e = col0 + wc + 16 * j + cB;
            Ob[(size_t)(m0 + 0) * 1024 + e] = acc[i][j][0] * i0;
            Ob[(size_t)(m0 + 1) * 1024 + e] = acc[i][j][1] * i1;
            Ob[(size_t)(m0 + 2) * 1024 + e] = acc[i][j][2] * i2;
            Ob[(size_t)(m0 + 3) * 1024 + e] = acc[i][j][3] * i3;
        }
    }
}

// ---------------------------------------------------------------- residual + LayerNorm (in place on out)
__global__ __launch_bounds__(256)
void residual_ln(const float* __restrict__ emb, float* __restrict__ out,
                 const float* __restrict__ gamma, const float* __restrict__ beta) {
    const size_t row = blockIdx.x;
    const int t = threadIdx.x;
    const int wv = t >> 6, lane = t & 63;
    const size_t base = row * 1024 + t * 4;

    float4 ev = *(const float4*)(emb + base);
    float4 ov = *(const float4*)(out + base);
    float x0 = ev.x + ov.x, x1 = ev.y + ov.y, x2 = ev.z + ov.z, x3 = ev.w + ov.w;

    float s = x0 + x1 + x2 + x3;
    float q = x0 * x0 + x1 * x1 + x2 * x2 + x3 * x3;
    s = wred_sum(s);
    q = wred_sum(q);
    __shared__ float s1[4], s2[4];
    if (lane == 0) { s1[wv] = s; s2[wv] = q; }
    __syncthreads();
    s = s1[0] + s1[1] + s1[2] + s1[3];
    q = s2[0] + s2[1] + s2[2] + s2[3];

    const float mu  = s * (1.0f / 1024.0f);
    const float var = q * (1.0f / 1024.0f) - mu * mu;
    const float r   = rsqrtf(var + 1e-5f);

    float4 g  = *(const float4*)(gamma + t * 4);
    float4 be = *(const float4*)(beta + t * 4);
    float4 res;
    res.x = (x0 - mu) * r * g.x + be.x;
    res.y = (x1 - mu) * r * g.y + be.y;
    res.z = (x2 - mu) * r * g.z + be.z;
    res.w = (x3 - mu) * r * g.w + be.w;
    *(float4*)(out + base) = res;
}

// ---------------------------------------------------------------- launch
extern "C" void kernel_launch(void* const* d_in, const int* in_sizes, int n_in,
                              void* d_out, int out_size, void* d_ws, size_t ws_size,
                              hipStream_t stream) {
    const float* emb   = (const float*)d_in[0];
    const float* Wq    = (const float*)d_in[4];
    const float* bq    = (const float*)d_in[5];
    const float* Wk    = (const float*)d_in[6];
    const float* bk    = (const float*)d_in[7];
    const float* Wv    = (const float*)d_in[8];
    const float* bv    = (const float*)d_in[9];
    const float* gamma = (const float*)d_in[10];
    const float* beta  = (const float*)d_in[11];
    float* out = (float*)d_out;

    char* ws = (char*)d_ws;
    // ws layout (bytes), with time-based reuse:
    //   [0,          33554432)  phase1: Xbf bf16 [16384,1024]
    //                           phase2: VT8 fp8 [4][1024][4096] at 0 (16,777,216)
    //                                   P0  fp8 [4096,4096]     at 16,777,216
    //   [33554432,   39845888)  phase1: Wbf bf16 [3072,1024]
    //                           phase2: sums f32 [4][4096] at 33,554,432 (65,536 B)
    //   [39845888,   73400320)  Qbf bf16 [4][4096,1024]; Q0Q1 dead after S(1) -> P3
    //   [73400320,  106954752)  Kbf bf16 [4][4096,1024]
    //   [106954752, 140509184)  phase1: Vt bf16 [4][1024][4096]
    //                           phase2 (after cast_v_fp8): P1, P2 fp8
    if (ws_size < 140509184u) return;
    u16* Xbf = (u16*)(ws);
    u16* Wbf = (u16*)(ws + 33554432);
    u16* Qbf = (u16*)(ws + 39845888);
    u16* Kbf = (u16*)(ws + 73400320);
    u16* VTB = (u16*)(ws + 106954752);

    u8*    VT8  = (u8*)(ws);
    u8*    P0   = (u8*)(ws + 16777216);
    float* SUMS = (float*)(ws + 33554432);
    u8*    P1   = (u8*)(ws + 106954752);
    u8*    P2   = (u8*)(ws + 123731968);
    u8*    P3   = (u8*)(ws + 39845888);
    u8*    Pb[4] = {P0, P1, P2, P3};

    cast_bf16<<<16384, 256, 0, stream>>>(emb, Xbf, 4194304);
    cast_bf16<<<1024, 256, 0, stream>>>(Wq, Wbf,           262144);
    cast_bf16<<<1024, 256, 0, stream>>>(Wk, Wbf + 1048576, 262144);
    cast_bf16<<<1024, 256, 0, stream>>>(Wv, Wbf + 2097152, 262144);

    // fused QKV projection: [16384,3072] = Xbf @ Wbf^T + bias; V transposed to VTB (bf16)
    gemm_bt<0, 128><<<dim3(24, 128), 256, 0, stream>>>(Xbf, Wbf, 1024,
        Qbf, Kbf, VTB, bq, bk, bv, nullptr, nullptr, 1.0f);

    // V bf16 -> fp8 (VTB dead afterwards; its space becomes P1/P2)
    cast_v_fp8<<<8192, 256, 0, stream>>>(VTB, VT8, 2097152);

    // zero the softmax-denominator accumulators (Wbf dead after QKV)
    hipMemsetAsync(SUMS, 0, 65536, stream);

    // S(b) = exp(Q_b K_b^T / 32) -> fp8 P_b + row sums
    for (int b = 0; b < 4; ++b) {
        const size_t o = (size_t)b * 4194304;
        gemm_bt<1, 128><<<dim3(32, 32), 256, 0, stream>>>(Qbf + o, Kbf + o, 1024,
            nullptr, nullptr, nullptr, nullptr, nullptr, nullptr,
            Pb[b], SUMS + b * 4096, 0.03125f);
    }

    // batched PV: O[b] = (P_b @ V_b) / rowsum -> fp32 out
    pv_fp8<<<dim3(8, 32, 4), 256, 0, stream>>>(P0, P1, P2, P3, VT8, SUMS, out);

    residual_ln<<<16384, 256, 0, stream>>>(emb, out, gamma, beta);
}

// Round 5
// 586.176 us; speedup vs baseline: 1.3693x; 1.2675x over previous
//
#include <hip/hip_runtime.h>
#include <hip/hip_fp8.h>

typedef unsigned short u16;
typedef unsigned char  u8;
typedef long long      i64;
using bf16x8 = __attribute__((ext_vector_type(8))) __bf16;
using f32x4  = __attribute__((ext_vector_type(4))) float;

__device__ __forceinline__ u16 f2bf(float f) {
    unsigned u = __builtin_bit_cast(unsigned, f);
    u += 0x7fffu + ((u >> 16) & 1u);
    return (u16)(u >> 16);
}
__device__ __forceinline__ float bf2f(u16 h) {
    unsigned u = ((unsigned)h) << 16;
    return __builtin_bit_cast(float, u);
}
__device__ __forceinline__ u8 f2fp8(float f) {
    __hip_fp8_e4m3 t(f);
    return t.__x;
}
__device__ __forceinline__ float wred_sum(float v) {
    #pragma unroll
    for (int o = 32; o; o >>= 1) v += __shfl_xor(v, o, 64);
    return v;
}

// async global->LDS, 16B per lane. LDS dest must be wave-uniform base + lane*16.
__device__ __forceinline__ void gl2lds16(const void* g, void* l) {
    __builtin_amdgcn_global_load_lds(
        (__attribute__((address_space(1))) void*)(g),
        (__attribute__((address_space(3))) void*)(l), 16, 0, 0);
}

// ---------------------------------------------------------------- cast fp32->bf16
__global__ __launch_bounds__(256)
void cast_bf16(const float* __restrict__ src, u16* __restrict__ dst, int n4) {
    int i = blockIdx.x * 256 + threadIdx.x;
    if (i < n4) {
        float4 f = ((const float4*)src)[i];
        ushort4 u;
        u.x = f2bf(f.x); u.y = f2bf(f.y); u.z = f2bf(f.z); u.w = f2bf(f.w);
        ((ushort4*)dst)[i] = u;
    }
}

// ---------------------------------------------------------------- cast bf16 -> fp8 e4m3 (8 elems/thread)
__global__ __launch_bounds__(256)
void cast_v_fp8(const u16* __restrict__ src, u8* __restrict__ dst, int n8) {
    int i = blockIdx.x * 256 + threadIdx.x;
    if (i < n8) {
        ushort4 a = ((const ushort4*)src)[2 * i];
        ushort4 b = ((const ushort4*)src)[2 * i + 1];
        union { u8 c[8]; unsigned long long q; } r;
        r.c[0] = f2fp8(bf2f(a.x)); r.c[1] = f2fp8(bf2f(a.y));
        r.c[2] = f2fp8(bf2f(a.z)); r.c[3] = f2fp8(bf2f(a.w));
        r.c[4] = f2fp8(bf2f(b.x)); r.c[5] = f2fp8(bf2f(b.y));
        r.c[6] = f2fp8(bf2f(b.z)); r.c[7] = f2fp8(bf2f(b.w));
        ((unsigned long long*)dst)[i] = r.q;
    }
}

// ---------------------------------------------------------------- GEMM C = A * Bt^T (bf16 inputs)
// A: [M,K] bf16 row-major.  Bt: [N,K] bf16 row-major (K contiguous). K=1024 here.
// Tile TM x 128, 256 threads (4 waves, 2x2), BK=32, mfma 16x16x32, direct-to-LDS staging.
// LDS tiles are 16B-chunk XOR-swizzled: physical chunk = logical chunk ^ ((row>>1)&3)
// (implemented by permuting which global chunk each lane stages).
// MODE 0: QKV projection epilogue (bias; Q,K bf16 row-major; V transposed via LDS to Vt bf16).
//         SWAP=true: blockIdx.x = row-tile, blockIdx.y = col-tile (XCD locality for X reuse).
// MODE 1: P = exp(acc*scale) -> fp8 e4m3 [.,4096], plus atomic row-sum accumulation into sums[].
template<int MODE, int TM, bool SWAP>
__global__ __launch_bounds__(256, 4)
void gemm_bt(const u16* __restrict__ A, const u16* __restrict__ Bt, const int K,
             u16* __restrict__ oQ, u16* __restrict__ oK, u16* __restrict__ oVt,
             const float* __restrict__ bQ, const float* __restrict__ bK,
             const float* __restrict__ bV,
             u8* __restrict__ oP, float* __restrict__ sums, const float scale)
{
    __shared__ u16 smem[TM * 32 + 128 * 32];
    u16* As = smem;
    u16* Bs = smem + TM * 32;

    constexpr int IM = TM / 32;
    const int tid  = threadIdx.x;
    const int wv   = tid >> 6;
    const int lane = tid & 63;
    const int wr   = (wv >> 1) * (TM / 2);
    const int wc   = (wv & 1) << 6;

    const int row0 = (SWAP ? blockIdx.x : blockIdx.y) * TM;
    const int col0 = (SWAP ? blockIdx.y : blockIdx.x) * 128;

    const int srow = tid >> 2;
    const int scol = (((tid & 3) ^ ((tid >> 3) & 3)) << 3);   // swizzled 16B chunk

    const u16* pA0 = A  + (size_t)(row0 + srow) * K + scol;
    const u16* pB0 = Bt + (size_t)(col0 + srow) * K + scol;

    char* aB0 = (char*)As + wv * 1024;
    char* aB1 = (char*)As + 4096 + wv * 1024;
    char* bB0 = (char*)Bs + wv * 1024;
    char* bB1 = (char*)Bs + 4096 + wv * 1024;

    const int fr = lane & 15;
    const int g  = lane >> 4;
    const int sw = (fr >> 1) & 3;
    const int kc = ((g ^ sw) << 3);     // swizzled chunk for fragment reads

    f32x4 acc[IM][4];
    #pragma unroll
    for (int i = 0; i < IM; i++)
        #pragma unroll
        for (int j = 0; j < 4; j++) acc[i][j] = (f32x4){0.f, 0.f, 0.f, 0.f};

    for (int k0 = 0; k0 < K; k0 += 32) {
        __syncthreads();
        gl2lds16(pA0 + k0, aB0);
        if (TM == 128) gl2lds16(pA0 + (size_t)64 * K + k0, aB1);
        gl2lds16(pB0 + k0, bB0);
        gl2lds16(pB0 + (size_t)64 * K + k0, bB1);
        __syncthreads();

        bf16x8 af[IM], bfr[4];
        #pragma unroll
        for (int i = 0; i < IM; i++) af[i]  = *(const bf16x8*)&As[(wr + 16 * i + fr) * 32 + kc];
        #pragma unroll
        for (int j = 0; j < 4; j++)  bfr[j] = *(const bf16x8*)&Bs[(wc + 16 * j + fr) * 32 + kc];
        #pragma unroll
        for (int i = 0; i < IM; i++)
            #pragma unroll
            for (int j = 0; j < 4; j++)
                acc[i][j] = __builtin_amdgcn_mfma_f32_16x16x32_bf16(af[i], bfr[j], acc[i][j], 0, 0, 0);
    }

    // epilogue: C/D layout col = lane&15, row = (lane>>4)*4 + reg
    const int rB = (lane >> 4) << 2;
    const int cB = lane & 15;

    if (MODE == 0) {
        const int sel = col0 >> 10;     // 0=Q 1=K 2=V
        if (sel < 2) {
            const float* bias = (sel == 0) ? bQ : bK;
            u16* dst = (sel == 0) ? oQ : oK;
            #pragma unroll
            for (int i = 0; i < IM; i++) {
                #pragma unroll
                for (int j = 0; j < 4; j++) {
                    const int m0 = row0 + wr + 16 * i + rB;
                    const int e  = (col0 & 1023) + wc + 16 * j + cB;
                    const float bb = bias[e];
                    #pragma unroll
                    for (int t = 0; t < 4; t++)
                        dst[(size_t)(m0 + t) * 1024 + e] = f2bf(acc[i][j][t] + bb);
                }
            }
        } else {
            // V: transpose 128x128 tile through LDS (XOR-swizzled), write Vt[b][e][n] bf16
            const int b      = row0 >> 12;
            const int n_base = row0 & 4095;
            const int e0     = col0 & 1023;
            __syncthreads();
            #pragma unroll
            for (int P = 0; P < 2; ++P) {
                if ((wc >> 6) == P) {
                    #pragma unroll
                    for (int i = 0; i < IM; i++) {
                        const int n_l0 = wr + 16 * i + rB;
                        const int hq   = n_l0 >> 3;
                        const int off  = n_l0 & 7;
                        #pragma unroll
                        for (int j = 0; j < 4; j++) {
                            const int e_p = 16 * j + cB;
                            const int hp  = hq ^ (e_p & 7);
                            const float bb = bV[e0 + P * 64 + e_p];
                            ushort4 pk;
                            pk.x = f2bf(acc[i][j][0] + bb);
                            pk.y = f2bf(acc[i][j][1] + bb);
                            pk.z = f2bf(acc[i][j][2] + bb);
                            pk.w = f2bf(acc[i][j][3] + bb);
                            *(ushort4*)&smem[e_p * 128 + hp * 8 + off] = pk;
                        }
                    }
                }
                __syncthreads();
                #pragma unroll
                for (int p4 = 0; p4 < 4; ++p4) {
                    const int idx = p4 * 256 + tid;
                    const int er  = idx >> 4;
                    const int c   = idx & 15;
                    const int cc  = c ^ (er & 7);
                    int4 v = *(const int4*)&smem[er * 128 + cc * 8];
                    *(int4*)&oVt[(size_t)b * 4194304 +
                                 (size_t)(e0 + P * 64 + er) * 4096 + n_base + c * 8] = v;
                }
                if (P == 0) __syncthreads();
            }
        }
    } else {
        // MODE 1: exp -> fp8 P + row-sum atomics
        float psum[IM][4];
        #pragma unroll
        for (int i = 0; i < IM; i++)
            #pragma unroll
            for (int t = 0; t < 4; t++) psum[i][t] = 0.f;

        #pragma unroll
        for (int i = 0; i < IM; i++) {
            #pragma unroll
            for (int j = 0; j < 4; j++) {
                const int m0 = row0 + wr + 16 * i + rB;
                const int c  = col0 + wc + 16 * j + cB;
                #pragma unroll
                for (int t = 0; t < 4; t++) {
                    const float e = __expf(acc[i][j][t] * scale);
                    psum[i][t] += e;
                    oP[(size_t)(m0 + t) * 4096 + c] = f2fp8(e);
                }
            }
        }
        #pragma unroll
        for (int i = 0; i < IM; i++) {
            #pragma unroll
            for (int t = 0; t < 4; t++) {
                float v = psum[i][t];
                v += __shfl_xor(v, 1, 64);
                v += __shfl_xor(v, 2, 64);
                v += __shfl_xor(v, 4, 64);
                v += __shfl_xor(v, 8, 64);
                if (cB == 0)
                    atomicAdd(&sums[row0 + wr + 16 * i + rB + t], v);
            }
        }
    }
}

// ---------------------------------------------------------------- batched PV, fp8: O[b][m][e] = sum_n P[m][n] Vt[e][n] / rowsum
// grid (32 m-tiles, 8 e-tiles, 4 batches): 32%8==0 pins all e-tiles of an
// m-tile to one XCD -> P fetched once per L2.  LDS 16B-chunk XOR swizzle as above.
__global__ __launch_bounds__(256, 4)
void pv_fp8(const u8* __restrict__ p0, const u8* __restrict__ p1,
            const u8* __restrict__ p2, const u8* __restrict__ p3,
            const u8* __restrict__ vt8, const float* __restrict__ sums,
            float* __restrict__ out)
{
    __shared__ u8 As[128 * 64];   // P tile: 128 m x 64 n
    __shared__ u8 Bs[128 * 64];   // Vt tile: 128 e x 64 n

    const int b = blockIdx.z;
    const u8* Pb = (b == 0) ? p0 : (b == 1) ? p1 : (b == 2) ? p2 : p3;
    const u8* Vb = vt8 + (size_t)b * 4194304;
    const float* sm = sums + (b << 12);
    float* Ob = out + (size_t)b * 4194304;

    const int tid = threadIdx.x, wv = tid >> 6, lane = tid & 63;
    const int wr = (wv >> 1) << 6, wc = (wv & 1) << 6;
    const int row0 = blockIdx.x << 7, col0 = blockIdx.y << 7;

    // staging with swizzled chunk selection
    const int sc8 = (((tid & 3) ^ ((tid >> 3) & 3)) << 4);   // byte offset of 16B chunk
    const u8* gA0 = Pb + (size_t)(row0 + (tid >> 2)) * 4096 + sc8;
    const u8* gA1 = gA0 + (size_t)64 * 4096;
    const u8* gB0 = Vb + (size_t)(col0 + (tid >> 2)) * 4096 + sc8;
    const u8* gB1 = gB0 + (size_t)64 * 4096;
    char* aL0 = (char*)As + wv * 1024;
    char* aL1 = (char*)As + 4096 + wv * 1024;
    char* bL0 = (char*)Bs + wv * 1024;
    char* bL1 = (char*)Bs + 4096 + wv * 1024;

    const int fr = lane & 15;
    const int g  = lane >> 4;
    const int sw = (fr >> 1) & 3;
    const int h8 = (g & 1) << 3;        // 8-byte half within chunk
    const int g2 = g >> 1;

    f32x4 acc[4][4];
    #pragma unroll
    for (int i = 0; i < 4; i++)
        #pragma unroll
        for (int j = 0; j < 4; j++) acc[i][j] = (f32x4){0.f, 0.f, 0.f, 0.f};

    for (int n0 = 0; n0 < 4096; n0 += 64) {
        __syncthreads();
        gl2lds16(gA0 + n0, aL0);
        gl2lds16(gA1 + n0, aL1);
        gl2lds16(gB0 + n0, bL0);
        gl2lds16(gB1 + n0, bL1);
        __syncthreads();
        #pragma unroll
        for (int kk = 0; kk < 64; kk += 32) {
            const int pc = (((kk >> 4) + g2) ^ sw) << 4;
            i64 af[4], bf[4];
            #pragma unroll
            for (int i = 0; i < 4; i++) af[i] = *(const i64*)&As[(wr + 16 * i + fr) * 64 + pc + h8];
            #pragma unroll
            for (int j = 0; j < 4; j++) bf[j] = *(const i64*)&Bs[(wc + 16 * j + fr) * 64 + pc + h8];
            #pragma unroll
            for (int i = 0; i < 4; i++)
                #pragma unroll
                for (int j = 0; j < 4; j++)
                    acc[i][j] = __builtin_amdgcn_mfma_f32_16x16x32_fp8_fp8(af[i], bf[j], acc[i][j], 0, 0, 0);
        }
    }

    const int rB = (lane >> 4) << 2, cB = lane & 15;
    #pragma unroll
    for (int i = 0; i < 4; i++) {
        const int m0 = row0 + wr + 16 * i + rB;
        const float i0 = 1.0f / sm[m0];
        const float i1 = 1.0f / sm[m0 + 1];
        const float i2 = 1.0f / sm[m0 + 2];
        const float i3 = 1.0f / sm[m0 + 3];
        #pragma unroll
        for (int j = 0; j < 4; j++) {
            const int e = col0 + wc + 16 * j + cB;
            Ob[(size_t)(m0 + 0) * 1024 + e] = acc[i][j][0] * i0;
            Ob[(size_t)(m0 + 1) * 1024 + e] = acc[i][j][1] * i1;
            Ob[(size_t)(m0 + 2) * 1024 + e] = acc[i][j][2] * i2;
            Ob[(size_t)(m0 + 3) * 1024 + e] = acc[i][j][3] * i3;
        }
    }
}

// ---------------------------------------------------------------- residual + LayerNorm (in place on out)
__global__ __launch_bounds__(256)
void residual_ln(const float* __restrict__ emb, float* __restrict__ out,
                 const float* __restrict__ gamma, const float* __restrict__ beta) {
    const size_t row = blockIdx.x;
    const int t = threadIdx.x;
    const int wv = t >> 6, lane = t & 63;
    const size_t base = row * 1024 + t * 4;

    float4 ev = *(const float4*)(emb + base);
    float4 ov = *(const float4*)(out + base);
    float x0 = ev.x + ov.x, x1 = ev.y + ov.y, x2 = ev.z + ov.z, x3 = ev.w + ov.w;

    float s = x0 + x1 + x2 + x3;
    float q = x0 * x0 + x1 * x1 + x2 * x2 + x3 * x3;
    s = wred_sum(s);
    q = wred_sum(q);
    __shared__ float s1[4], s2[4];
    if (lane == 0) { s1[wv] = s; s2[wv] = q; }
    __syncthreads();
    s = s1[0] + s1[1] + s1[2] + s1[3];
    q = s2[0] + s2[1] + s2[2] + s2[3];

    const float mu  = s * (1.0f / 1024.0f);
    const float var = q * (1.0f / 1024.0f) - mu * mu;
    const float r   = rsqrtf(var + 1e-5f);

    float4 g  = *(const float4*)(gamma + t * 4);
    float4 be = *(const float4*)(beta + t * 4);
    float4 res;
    res.x = (x0 - mu) * r * g.x + be.x;
    res.y = (x1 - mu) * r * g.y + be.y;
    res.z = (x2 - mu) * r * g.z + be.z;
    res.w = (x3 - mu) * r * g.w + be.w;
    *(float4*)(out + base) = res;
}

// ---------------------------------------------------------------- launch
extern "C" void kernel_launch(void* const* d_in, const int* in_sizes, int n_in,
                              void* d_out, int out_size, void* d_ws, size_t ws_size,
                              hipStream_t stream) {
    const float* emb   = (const float*)d_in[0];
    const float* Wq    = (const float*)d_in[4];
    const float* bq    = (const float*)d_in[5];
    const float* Wk    = (const float*)d_in[6];
    const float* bk    = (const float*)d_in[7];
    const float* Wv    = (const float*)d_in[8];
    const float* bv    = (const float*)d_in[9];
    const float* gamma = (const float*)d_in[10];
    const float* beta  = (const float*)d_in[11];
    float* out = (float*)d_out;

    char* ws = (char*)d_ws;
    // ws layout (bytes), with time-based reuse:
    //   [0,          33554432)  phase1: Xbf bf16 [16384,1024]
    //                           phase2: VT8 fp8 [4][1024][4096] at 0 (16,777,216)
    //                                   P0  fp8 [4096,4096]     at 16,777,216
    //   [33554432,   39845888)  phase1: Wbf bf16 [3072,1024]
    //                           phase2: sums f32 [4][4096] at 33,554,432 (65,536 B)
    //   [39845888,   73400320)  Qbf bf16 [4][4096,1024]; Q0Q1 dead after S(1) -> P3
    //   [73400320,  106954752)  Kbf bf16 [4][4096,1024]
    //   [106954752, 140509184)  phase1: Vt bf16 [4][1024][4096]
    //                           phase2 (after cast_v_fp8): P1, P2 fp8
    if (ws_size < 140509184u) return;
    u16* Xbf = (u16*)(ws);
    u16* Wbf = (u16*)(ws + 33554432);
    u16* Qbf = (u16*)(ws + 39845888);
    u16* Kbf = (u16*)(ws + 73400320);
    u16* VTB = (u16*)(ws + 106954752);

    u8*    VT8  = (u8*)(ws);
    u8*    P0   = (u8*)(ws + 16777216);
    float* SUMS = (float*)(ws + 33554432);
    u8*    P1   = (u8*)(ws + 106954752);
    u8*    P2   = (u8*)(ws + 123731968);
    u8*    P3   = (u8*)(ws + 39845888);
    u8*    Pb[4] = {P0, P1, P2, P3};

    cast_bf16<<<16384, 256, 0, stream>>>(emb, Xbf, 4194304);
    cast_bf16<<<1024, 256, 0, stream>>>(Wq, Wbf,           262144);
    cast_bf16<<<1024, 256, 0, stream>>>(Wk, Wbf + 1048576, 262144);
    cast_bf16<<<1024, 256, 0, stream>>>(Wv, Wbf + 2097152, 262144);

    // fused QKV projection: [16384,3072] = Xbf @ Wbf^T + bias; V transposed to VTB (bf16)
    // grid swapped (rows fastest) so each weight-tile pins to one XCD.
    gemm_bt<0, 128, true><<<dim3(128, 24), 256, 0, stream>>>(Xbf, Wbf, 1024,
        Qbf, Kbf, VTB, bq, bk, bv, nullptr, nullptr, 1.0f);

    // V bf16 -> fp8 (VTB dead afterwards; its space becomes P1/P2)
    cast_v_fp8<<<8192, 256, 0, stream>>>(VTB, VT8, 2097152);

    // zero the softmax-denominator accumulators (Wbf dead after QKV)
    hipMemsetAsync(SUMS, 0, 65536, stream);

    // S(b) = exp(Q_b K_b^T / 32) -> fp8 P_b + row sums
    for (int b = 0; b < 4; ++b) {
        const size_t o = (size_t)b * 4194304;
        gemm_bt<1, 128, false><<<dim3(32, 32), 256, 0, stream>>>(Qbf + o, Kbf + o, 1024,
            nullptr, nullptr, nullptr, nullptr, nullptr, nullptr,
            Pb[b], SUMS + b * 4096, 0.03125f);
    }

    // batched PV: O[b] = (P_b @ V_b) / rowsum -> fp32 out
    pv_fp8<<<dim3(32, 8, 4), 256, 0, stream>>>(P0, P1, P2, P3, VT8, SUMS, out);

    residual_ln<<<16384, 256, 0, stream>>>(emb, out, gamma, beta);
}